// Round 1
// baseline (293.145 us; speedup 1.0000x reference)
//
#include <hip/hip_runtime.h>

// BlurNet: out[b,0,y,x] = w * bilinear_zero_pad(img[b,0], y+off_y, x+off_x) + bias
// img: [16,1,720,1280] f32, offset: [16,2,720,1280] f32 (ch0=off_y, ch1=off_x)

#define NB 16
#define IH 720
#define IW 1280

__global__ __launch_bounds__(256) void blurnet_kernel(
    const float* __restrict__ img,      // [B,1,H,W]
    const float* __restrict__ offset,   // [B,2,H,W]
    const float* __restrict__ weight,   // [1]
    const float* __restrict__ bias,     // [1]
    float* __restrict__ out)            // [B,1,H,W]
{
    const int HW = IH * IW;
    int i4 = blockIdx.x * blockDim.x + threadIdx.x;
    int p = i4 * 4;                      // first pixel of this thread's quad
    if (p >= NB * HW) return;

    int b   = p / HW;
    int rem = p - b * HW;
    int y   = rem / IW;
    int x   = rem - y * IW;              // multiple of 4; quad stays in-row

    const float* imgb = img + b * HW;
    const float4 oy = *reinterpret_cast<const float4*>(offset + (size_t)b * 2 * HW + rem);
    const float4 ox = *reinterpret_cast<const float4*>(offset + (size_t)b * 2 * HW + HW + rem);

    const float w  = weight[0];
    const float bs = bias[0];

    float oys[4] = {oy.x, oy.y, oy.z, oy.w};
    float oxs[4] = {ox.x, ox.y, ox.z, ox.w};
    float res[4];

    #pragma unroll
    for (int k = 0; k < 4; ++k) {
        float py = (float)y + oys[k];
        float px = (float)(x + k) + oxs[k];
        float fy0 = floorf(py);
        float fx0 = floorf(px);
        int   y0  = (int)fy0;
        int   x0  = (int)fx0;
        float wy1 = py - fy0, wy0 = 1.0f - wy1;
        float wx1 = px - fx0, wx0 = 1.0f - wx1;

        bool yv0 = (y0 >= 0)     && (y0 < IH);
        bool yv1 = (y0 + 1 >= 0) && (y0 + 1 < IH);
        bool xv0 = (x0 >= 0)     && (x0 < IW);
        bool xv1 = (x0 + 1 >= 0) && (x0 + 1 < IW);

        float v00 = 0.0f, v01 = 0.0f, v10 = 0.0f, v11 = 0.0f;
        if (yv0 && xv0) v00 = imgb[y0 * IW + x0];
        if (yv0 && xv1) v01 = imgb[y0 * IW + x0 + 1];
        if (yv1 && xv0) v10 = imgb[(y0 + 1) * IW + x0];
        if (yv1 && xv1) v11 = imgb[(y0 + 1) * IW + x0 + 1];

        float s = wy0 * (wx0 * v00 + wx1 * v01) + wy1 * (wx0 * v10 + wx1 * v11);
        res[k] = w * s + bs;
    }

    *reinterpret_cast<float4*>(out + p) = make_float4(res[0], res[1], res[2], res[3]);
}

extern "C" void kernel_launch(void* const* d_in, const int* in_sizes, int n_in,
                              void* d_out, int out_size, void* d_ws, size_t ws_size,
                              hipStream_t stream) {
    const float* img = (const float*)d_in[0];
    const float* off = (const float*)d_in[1];
    const float* wt  = (const float*)d_in[2];
    const float* bs  = (const float*)d_in[3];
    float* out = (float*)d_out;

    const int total4 = NB * IH * IW / 4;   // 3,686,400 quads
    const int threads = 256;
    const int blocks = (total4 + threads - 1) / threads;  // 14,400
    blurnet_kernel<<<blocks, threads, 0, stream>>>(img, off, wt, bs, out);
}

// Round 2
// 235.615 us; speedup vs baseline: 1.2442x; 1.2442x over previous
//
#include <hip/hip_runtime.h>

// BlurNet: out[b,0,y,x] = w * bilinear_zero_pad(img[b,0], y+off_y, x+off_x) + bias
// img: [16,1,720,1280] f32, offset: [16,2,720,1280] f32 (ch0=off_y, ch1=off_x)
//
// Strategy: offsets ~ N(0,1) => samples land within a few px of the identity
// grid. Stage the tile's image window (+halo) in LDS via coalesced float4
// loads; gather the 4 bilinear corners from LDS. Rare out-of-halo samples
// (P(|N|>6) ~ 2e-9 per sample) fall back to predicated global loads, so the
// result is exact regardless of offset magnitude. Border zero-padding is
// reproduced by staging 0.0f for out-of-image texels.

#define NB 16
#define IH 720
#define IW 1280
#define TW 128          // tile width  (10 tiles)
#define TH 16           // tile height (45 tiles)
#define HALO_Y 6        // vertical halo rows each side
#define HX_L 8          // left x halo (chosen so staged cols start 16B-aligned)
#define SROWS (TH + 2*HALO_Y + 1)   // 29 staged rows: [ty0-6, ty0+22]
#define SCOLS 148                   // staged cols:  [tx0-8, tx0+139]
#define SLOTQ (SCOLS/4)             // 37 float4 slots per row
#define SLOTS (SROWS * SLOTQ)       // 1073

__global__ __launch_bounds__(256) void blurnet_tile(
    const float* __restrict__ img,
    const float* __restrict__ offset,
    const float* __restrict__ weight,
    const float* __restrict__ bias,
    float* __restrict__ out)
{
    __shared__ float ls[SROWS][SCOLS];

    const int HW = IH * IW;
    const int tilesX = IW / TW;              // 10
    const int tilesY = IH / TH;              // 45
    const int nwg = NB * tilesX * tilesY;    // 7200 (% 8 == 0)

    // XCD-aware bijective swizzle: each XCD gets a contiguous chunk of tiles.
    int bid = blockIdx.x;
    int tile = (bid & 7) * (nwg >> 3) + (bid >> 3);

    int b  = tile / (tilesX * tilesY);
    int tr = tile % (tilesX * tilesY);
    int ty0 = (tr / tilesX) * TH;
    int tx0 = (tr % tilesX) * TW;

    const float* imgb = img + b * HW;

    // ---- stage image window into LDS (coalesced float4, zero-pad OOB) ----
    for (int s = threadIdx.x; s < SLOTS; s += 256) {
        int r  = s / SLOTQ;
        int c4 = s % SLOTQ;
        int gr = ty0 - HALO_Y + r;
        int gc = tx0 - HX_L + c4 * 4;        // multiple of 4 => 16B-aligned
        float4 v;
        if (gr >= 0 && gr < IH && gc >= 0 && gc + 3 < IW) {
            v = *reinterpret_cast<const float4*>(imgb + gr * IW + gc);
        } else {
            float t0 = 0.f, t1 = 0.f, t2 = 0.f, t3 = 0.f;
            if (gr >= 0 && gr < IH) {
                if (gc     >= 0 && gc     < IW) t0 = imgb[gr * IW + gc];
                if (gc + 1 >= 0 && gc + 1 < IW) t1 = imgb[gr * IW + gc + 1];
                if (gc + 2 >= 0 && gc + 2 < IW) t2 = imgb[gr * IW + gc + 2];
                if (gc + 3 >= 0 && gc + 3 < IW) t3 = imgb[gr * IW + gc + 3];
            }
            v = make_float4(t0, t1, t2, t3);
        }
        *reinterpret_cast<float4*>(&ls[r][c4 * 4]) = v;
    }
    __syncthreads();

    const float w   = weight[0];
    const float bsv = bias[0];
    const float* offy = offset + (size_t)b * 2 * HW;
    const float* offx = offy + HW;

    // ---- 512 quads of 4 px; thread handles quads tid and tid+256 ----
    #pragma unroll
    for (int qq = 0; qq < 2; ++qq) {
        int q   = threadIdx.x + qq * 256;
        int row = q >> 5;                    // 32 quads per 128-wide row
        int col = (q & 31) << 2;
        int gy  = ty0 + row;
        int gx0 = tx0 + col;
        int base = gy * IW + gx0;

        float4 oy = *reinterpret_cast<const float4*>(offy + base);
        float4 ox = *reinterpret_cast<const float4*>(offx + base);
        float oys[4] = {oy.x, oy.y, oy.z, oy.w};
        float oxs[4] = {ox.x, ox.y, ox.z, ox.w};
        float res[4];

        #pragma unroll
        for (int k = 0; k < 4; ++k) {
            float py = (float)gy + oys[k];
            float px = (float)(gx0 + k) + oxs[k];
            float fy0 = floorf(py);
            float fx0 = floorf(px);
            int y0 = (int)fy0;
            int x0 = (int)fx0;
            float wy1 = py - fy0, wy0 = 1.0f - wy1;
            float wx1 = px - fx0, wx0 = 1.0f - wx1;

            int lr = y0 - (ty0 - HALO_Y);
            int lc = x0 - (tx0 - HX_L);
            float v00, v01, v10, v11;
            if (lr >= 0 && lr + 1 < SROWS && lc >= 0 && lc + 1 < SCOLS) {
                v00 = ls[lr][lc];
                v01 = ls[lr][lc + 1];
                v10 = ls[lr + 1][lc];
                v11 = ls[lr + 1][lc + 1];
            } else {
                // rare fallback: exact predicated global gathers (zero pad)
                bool yv0 = (y0 >= 0)     && (y0 < IH);
                bool yv1 = (y0 + 1 >= 0) && (y0 + 1 < IH);
                bool xv0 = (x0 >= 0)     && (x0 < IW);
                bool xv1 = (x0 + 1 >= 0) && (x0 + 1 < IW);
                v00 = (yv0 && xv0) ? imgb[y0 * IW + x0]           : 0.0f;
                v01 = (yv0 && xv1) ? imgb[y0 * IW + x0 + 1]       : 0.0f;
                v10 = (yv1 && xv0) ? imgb[(y0 + 1) * IW + x0]     : 0.0f;
                v11 = (yv1 && xv1) ? imgb[(y0 + 1) * IW + x0 + 1] : 0.0f;
            }
            float s = wy0 * (wx0 * v00 + wx1 * v01) + wy1 * (wx0 * v10 + wx1 * v11);
            res[k] = w * s + bsv;
        }
        *reinterpret_cast<float4*>(out + (size_t)b * HW + base) =
            make_float4(res[0], res[1], res[2], res[3]);
    }
}

extern "C" void kernel_launch(void* const* d_in, const int* in_sizes, int n_in,
                              void* d_out, int out_size, void* d_ws, size_t ws_size,
                              hipStream_t stream) {
    const float* img = (const float*)d_in[0];
    const float* off = (const float*)d_in[1];
    const float* wt  = (const float*)d_in[2];
    const float* bs  = (const float*)d_in[3];
    float* out = (float*)d_out;

    const int blocks = NB * (IH / TH) * (IW / TW);   // 7200
    blurnet_tile<<<blocks, 256, 0, stream>>>(img, off, wt, bs, out);
}